// Round 6
// baseline (573.832 us; speedup 1.0000x reference)
//
#include <hip/hip_runtime.h>

#define DD 64
#define ROW 256        // output row stride in floats: D*(L+1)
#define CHUNK 1024     // scan chunk

// ---- init: copy entity_embed -> out slice 0, AND zero counts ----------------
__global__ void k_init(const float* __restrict__ ent, float* __restrict__ out,
                       int* __restrict__ counts, int n_rows, int copy_blocks) {
    if ((int)blockIdx.x < copy_blocks) {
        int idx = blockIdx.x * 256 + threadIdx.x;   // over n_rows*16 float4s
        int total = n_rows * 16;
        if (idx >= total) return;
        int n = idx >> 4, q = idx & 15;
        ((float4*)(out + (long)n * ROW))[q] = ((const float4*)(ent + (long)n * DD))[q];
    } else {
        int i = (blockIdx.x - copy_blocks) * 256 + threadIdx.x;
        if (i < n_rows) counts[i] = 0;
    }
}

// ---- count + rank: rank[e] = old count (removes scatter's atomic) -----------
__global__ void k_count_rank(const int* __restrict__ heads, int* __restrict__ counts,
                             int* __restrict__ rank, int nE) {
    int e = blockIdx.x * 256 + threadIdx.x;
    if (e >= nE) return;
    rank[e] = atomicAdd(counts + heads[e], 1);
}

// ---- fallback count (small ws) ----------------------------------------------
__global__ void k_count(const int* __restrict__ heads, int* __restrict__ counts, int nE) {
    int e = blockIdx.x * 256 + threadIdx.x;
    if (e >= nE) return;
    atomicAdd(counts + heads[e], 1);
}

// ---- scan step 1: per-chunk exclusive scan + chunk totals -------------------
__global__ __launch_bounds__(256) void k_scan_chunk(
        const int* __restrict__ counts, int* __restrict__ offs,
        int* __restrict__ partials, int n) {
    __shared__ int lds[256];
    int base = blockIdx.x * CHUNK;
    int t = threadIdx.x;
    int c[4]; int sum = 0;
    #pragma unroll
    for (int j = 0; j < 4; ++j) {
        int i = base + t * 4 + j;
        c[j] = (i < n) ? counts[i] : 0;
        sum += c[j];
    }
    lds[t] = sum; __syncthreads();
    for (int d = 1; d < 256; d <<= 1) {
        int v = (t >= d) ? lds[t - d] : 0;
        __syncthreads();
        lds[t] += v;
        __syncthreads();
    }
    int excl = lds[t] - sum;
    if (t == 255) partials[blockIdx.x] = lds[255];
    int run = excl;
    #pragma unroll
    for (int j = 0; j < 4; ++j) {
        int i = base + t * 4 + j;
        if (i < n) offs[i] = run;
        run += c[j];
    }
}

// ---- scan step 2 (fused): every block redundantly scans the <=128 partials,
// then adds chunk offset; optionally writes scatter cursors (fallback path) ---
__global__ __launch_bounds__(256) void k_scan_add(
        int* __restrict__ offs, int* __restrict__ cursors,
        const int* __restrict__ partials, int n, int nE, int nb, int write_cursors) {
    __shared__ int lds[128];
    int t = threadIdx.x;
    int v = 0;
    if (t < 128) { v = (t < nb) ? partials[t] : 0; lds[t] = v; }
    __syncthreads();
    for (int d = 1; d < 128; d <<= 1) {
        int u = (t >= d && t < 128) ? lds[t - d] : 0;
        __syncthreads();
        if (t < 128) lds[t] += u;
        __syncthreads();
    }
    if (t < 128) lds[t] -= v;      // exclusive
    __syncthreads();
    int i = blockIdx.x * 256 + t;
    if (i < n) {
        int val = offs[i] + lds[i >> 10];
        offs[i] = val;
        if (write_cursors) cursors[i] = val;
    } else if (i == n) {
        offs[n] = nE;
    }
}

// ---- scatter, rank path: pure store, zero atomics ---------------------------
__global__ void k_scatter_rank(const int* __restrict__ heads, const int* __restrict__ rels,
                               const int* __restrict__ tails, const int* __restrict__ offs,
                               const int* __restrict__ rank, int* __restrict__ packed, int nE) {
    int e = blockIdx.x * 256 + threadIdx.x;
    if (e >= nE) return;
    packed[offs[heads[e]] + rank[e]] = tails[e] | (rels[e] << 20);
}

// ---- scatter, fallback path (atomic cursor) ---------------------------------
__global__ void k_scatter(const int* __restrict__ heads, const int* __restrict__ rels,
                          const int* __restrict__ tails, int* __restrict__ running,
                          int* __restrict__ packed, int nE) {
    int e = blockIdx.x * 256 + threadIdx.x;
    if (e >= nE) return;
    int pos = atomicAdd(running + heads[e], 1);
    packed[pos] = tails[e] | (rels[e] << 20);
}

// ---- fused KGAT layer v3 ----------------------------------------------------
// 16-lane group per head, 4 heads/wave. Descriptors are group-broadcast loads;
// 2-edge pipeline per group => 8 edge gather-pairs in flight per wave.
// ssum is group-uniform (no cross-group combine). Epilogue reuses Wt reads 4x.
__global__ __launch_bounds__(256) void k_layer(
        const int* __restrict__ offs, const int* __restrict__ packed,
        const float* __restrict__ hbase, const float* __restrict__ relemb,
        const float* __restrict__ W, float* __restrict__ outbase,
        int n_heads, int nE) {
    __shared__ float Wt[DD * 65];      // padded transpose: Wt[k*65+j] = W[j][k]
    __shared__ float xs[4][4][DD];     // [wave][group-head][dim]
    for (int idx = threadIdx.x; idx < DD * DD; idx += 256)
        Wt[(idx & 63) * 65 + (idx >> 6)] = W[idx];   // 2-way bank alias: free
    __syncthreads();

    int w = threadIdx.x >> 6, lane = threadIdx.x & 63;
    int g = lane >> 4, s = lane & 15;      // group 0..3, sublane 0..15

    int hd0 = blockIdx.x * 16 + w * 4;
    if (hd0 >= n_heads) return;            // no barriers after this point
    int hd = hd0 + g;
    int hdc = (hd < n_heads) ? hd : 0;

    const float4 eh4 = *(const float4*)(hbase + (long)hdc * ROW + 4 * s);
    int p  = offs[hdc];                    // group-uniform broadcast loads
    int pe = offs[hdc + 1];

    // wave max of remaining edges (groups live at lane>>4, xor 16/32 mixes groups)
    int rem = pe - p;
    int m = rem;
    m = max(m, __shfl_xor(m, 16));
    m = max(m, __shfl_xor(m, 32));

    float4 acc = make_float4(0.f, 0.f, 0.f, 0.f);
    float ssum = 0.f;

    int pc = p;
    int v0 = packed[min(pc,     nE - 1)];
    int v1 = packed[min(pc + 1, nE - 1)];
    float4 tt0 = *(const float4*)(hbase + (long)(v0 & 0xFFFFF) * ROW + 4 * s);
    float4 rr0 = *(const float4*)(relemb + (v0 >> 20) * DD + 4 * s);
    float4 tt1 = *(const float4*)(hbase + (long)(v1 & 0xFFFFF) * ROW + 4 * s);
    float4 rr1 = *(const float4*)(relemb + (v1 >> 20) * DD + 4 * s);

    for (int it = 0; it < m; it += 2) {
        int va = packed[min(pc + 2, nE - 1)];
        int vb = packed[min(pc + 3, nE - 1)];
        float4 tta = *(const float4*)(hbase + (long)(va & 0xFFFFF) * ROW + 4 * s);
        float4 rra = *(const float4*)(relemb + (va >> 20) * DD + 4 * s);
        float4 ttb = *(const float4*)(hbase + (long)(vb & 0xFFFFF) * ROW + 4 * s);
        float4 rrb = *(const float4*)(relemb + (vb >> 20) * DD + 4 * s);

        // ---- stage 0: edge pc ----
        {
            float sc = 0.f;
            #pragma unroll
            for (int q = 0; q < 4; ++q) {
                float xq = (&eh4.x)[q] + (&rr0.x)[q];
                float t = __expf(2.f * xq);
                float th = 1.f - 2.f * __builtin_amdgcn_rcpf(t + 1.f);
                sc += (&tt0.x)[q] * th;
            }
            #pragma unroll
            for (int off = 1; off <= 8; off <<= 1) sc += __shfl_xor(sc, off);
            float se = (pc < pe) ? __expf(sc) : 0.f;
            ssum += se;
            acc.x += se * tt0.x; acc.y += se * tt0.y;
            acc.z += se * tt0.z; acc.w += se * tt0.w;
        }
        // ---- stage 1: edge pc+1 ----
        {
            float sc = 0.f;
            #pragma unroll
            for (int q = 0; q < 4; ++q) {
                float xq = (&eh4.x)[q] + (&rr1.x)[q];
                float t = __expf(2.f * xq);
                float th = 1.f - 2.f * __builtin_amdgcn_rcpf(t + 1.f);
                sc += (&tt1.x)[q] * th;
            }
            #pragma unroll
            for (int off = 1; off <= 8; off <<= 1) sc += __shfl_xor(sc, off);
            float se = (pc + 1 < pe) ? __expf(sc) : 0.f;
            ssum += se;
            acc.x += se * tt1.x; acc.y += se * tt1.y;
            acc.z += se * tt1.z; acc.w += se * tt1.w;
        }
        pc += 2;
        tt0 = tta; rr0 = rra; tt1 = ttb; rr1 = rrb;
    }

    // finalize this group's head: x = eh + agg/ssum (ssum group-uniform)
    float inv = __builtin_amdgcn_rcpf(ssum + 1e-10f);
    float4 x4;
    x4.x = eh4.x + acc.x * inv;  x4.y = eh4.y + acc.y * inv;
    x4.z = eh4.z + acc.z * inv;  x4.w = eh4.w + acc.w * inv;
    *(float4*)(&xs[w][g][4 * s]) = x4;     // wave-private: no barrier

    // epilogue: 4 heads, y_h[lane] = leaky_relu(dot(xs[h], Wt[:,lane]))
    const float* xw = &xs[w][0][0];
    float y0 = 0.f, y1 = 0.f, y2 = 0.f, y3 = 0.f;
    #pragma unroll
    for (int k4 = 0; k4 < DD; k4 += 4) {
        float4 a0 = *(const float4*)(xw + 0 * DD + k4);   // broadcast reads
        float4 a1 = *(const float4*)(xw + 1 * DD + k4);
        float4 a2 = *(const float4*)(xw + 2 * DD + k4);
        float4 a3 = *(const float4*)(xw + 3 * DD + k4);
        float w0 = Wt[(k4 + 0) * 65 + lane];
        float w1 = Wt[(k4 + 1) * 65 + lane];
        float w2 = Wt[(k4 + 2) * 65 + lane];
        float w3 = Wt[(k4 + 3) * 65 + lane];
        y0 += a0.x * w0 + a0.y * w1 + a0.z * w2 + a0.w * w3;
        y1 += a1.x * w0 + a1.y * w1 + a1.z * w2 + a1.w * w3;
        y2 += a2.x * w0 + a2.y * w1 + a2.z * w2 + a2.w * w3;
        y3 += a3.x * w0 + a3.y * w1 + a3.z * w2 + a3.w * w3;
    }
    y0 = y0 >= 0.f ? y0 : 0.2f * y0;
    y1 = y1 >= 0.f ? y1 : 0.2f * y1;
    y2 = y2 >= 0.f ? y2 : 0.2f * y2;
    y3 = y3 >= 0.f ? y3 : 0.2f * y3;
    if (hd0 + 0 < n_heads) outbase[(long)(hd0 + 0) * ROW + lane] = y0;
    if (hd0 + 1 < n_heads) outbase[(long)(hd0 + 1) * ROW + lane] = y1;
    if (hd0 + 2 < n_heads) outbase[(long)(hd0 + 2) * ROW + lane] = y2;
    if (hd0 + 3 < n_heads) outbase[(long)(hd0 + 3) * ROW + lane] = y3;
}

extern "C" void kernel_launch(void* const* d_in, const int* in_sizes, int n_in,
                              void* d_out, int out_size, void* d_ws, size_t ws_size,
                              hipStream_t stream) {
    const int*   heads = (const int*)d_in[0];
    const int*   rels  = (const int*)d_in[1];
    const int*   tails = (const int*)d_in[2];
    const float* ent   = (const float*)d_in[3];
    const float* rel   = (const float*)d_in[4];
    const float* Ws    = (const float*)d_in[5];
    float* out = (float*)d_out;

    const int nE = in_sizes[0];
    const int N  = in_sizes[3] / DD;
    const int L  = in_sizes[5] / (DD * DD);
    const int NREL = in_sizes[4] / (L * DD);

    int* offs   = (int*)d_ws;            // [N+1]
    int* counts = offs + (N + 1);        // [N] (counts; cursors in fallback)
    int* packed = counts + N;            // [E]
    int* rank   = packed + nE;           // [E] (rank path only)
    // partials in the TAIL of packed: consumed by k_scan_add strictly BEFORE
    // the scatter writes packed (stream order). 128 slots >= nchunks.
    int* partials = packed + nE - 128;

    size_t need_rank = ((size_t)(2 * N + 1) + 2 * (size_t)nE) * sizeof(int);
    int use_rank = (ws_size >= need_rank) ? 1 : 0;   // constant across calls

    dim3 blk(256);
    int copy_blocks = (N * 16 + 255) / 256;
    int zero_blocks = (N + 255) / 256;
    int edge_blocks = (nE + 255) / 256;
    int nchunks = (N + CHUNK - 1) / CHUNK;   // 98 for N=100000

    k_init<<<copy_blocks + zero_blocks, blk, 0, stream>>>(ent, out, counts, N, copy_blocks);
    if (use_rank)
        k_count_rank<<<edge_blocks, blk, 0, stream>>>(heads, counts, rank, nE);
    else
        k_count<<<edge_blocks, blk, 0, stream>>>(heads, counts, nE);
    k_scan_chunk<<<nchunks, blk, 0, stream>>>(counts, offs, partials, N);
    k_scan_add<<<(N + 1 + 255) / 256, blk, 0, stream>>>(
        offs, counts, partials, N, nE, nchunks, use_rank ? 0 : 1);
    if (use_rank)
        k_scatter_rank<<<edge_blocks, blk, 0, stream>>>(heads, rels, tails, offs, rank, packed, nE);
    else
        k_scatter<<<edge_blocks, blk, 0, stream>>>(heads, rels, tails, counts, packed, nE);

    int layer_blocks = (N + 15) / 16;
    for (int l = 0; l < L; ++l) {
        k_layer<<<layer_blocks, blk, 0, stream>>>(
            offs, packed, out + l * DD, rel + (long)l * NREL * DD,
            Ws + (long)l * DD * DD, out + (l + 1) * DD, N, nE);
    }
}